// Round 3
// baseline (107.695 us; speedup 1.0000x reference)
//
#include <hip/hip_runtime.h>
#include <math.h>

// Fused diffusion-loss kernel.
// ws layout (doubles):
//   [0 .. 16*B)   per-batch stats atomics: W, Sw*p[3], Sw*g[3], Sw*p(x)g[9]
//   [16*B]        bond_sum atomic
//   [16*B+1]      (as uint32) block-completion counter
// kernel_launch memsets the first (16*B+2) doubles to 0.

#define RT 256   // rows per block (= threads)
#define CT 64    // cols per LDS tile
#define MAXB 8

__global__ __launch_bounds__(RT, 4)
void k_main(const float* __restrict__ pred, const float* __restrict__ gt,
            const float* __restrict__ ht, const float* __restrict__ w,
            float* __restrict__ out, double* __restrict__ ws,
            int N, int B, unsigned total) {
    const int b   = blockIdx.z;
    const int r0  = blockIdx.x * RT;
    const int c0  = blockIdx.y * CT;
    const int tid = threadIdx.x;
    const int lane = tid & 63, wave = tid >> 6;
    const float* p  = pred + (size_t)b * N * 3;
    const float* g  = gt   + (size_t)b * N * 3;
    const float* wb = w    + (size_t)b * N;
    double* stats = ws + (size_t)b * 16;
    double* bondp = ws + 16 * B;
    unsigned* cnt = (unsigned*)(ws + 16 * B + 1);

    __shared__ float4 sp4[CT], sg4[CT];
    __shared__ double shred[4][16];

    // symmetry: only pairs m > n contribute (x2); skip blocks fully below diag
    const bool bond_active = (c0 + CT > r0 + 1);

    const int n = r0 + tid;
    const bool row_ok = (n < N);
    float px=0.f,py=0.f,pz=0.f,gx=0.f,gy=0.f,gz=0.f,wn=0.f;
    if (row_ok) {
        px = p[3*n]; py = p[3*n+1]; pz = p[3*n+2];
        gx = g[3*n]; gy = g[3*n+1]; gz = g[3*n+2];
        wn = wb[n];
    }

    if (bond_active) {
        for (int i = tid; i < CT; i += RT) {
            int m = c0 + i;
            if (m < N) {
                sp4[i] = make_float4(p[3*m], p[3*m+1], p[3*m+2], wb[m]);
                sg4[i] = make_float4(g[3*m], g[3*m+1], g[3*m+2], 0.0f);
            } else {
                sp4[i] = make_float4(0.f,0.f,0.f,0.f);
                sg4[i] = make_float4(0.f,0.f,0.f,0.f);
            }
        }
        __syncthreads();
    }

    float bond_f = 0.0f;
    if (bond_active && row_ok && (c0 + CT - 1 > n)) {
        int cc = min(CT, N - c0);
        for (int i = 0; i < cc; i++) {
            float4 cp = sp4[i];
            float4 cg = sg4[i];
            float dxp = px-cp.x, dyp = py-cp.y, dzp = pz-cp.z;
            float dp  = sqrtf(dxp*dxp + dyp*dyp + dzp*dzp);
            float dxg = gx-cg.x, dyg = gy-cg.y, dzg = gz-cg.z;
            float dg  = sqrtf(dxg*dxg + dyg*dyg + dzg*dzg);
            float dd  = dp - dg;
            float t   = wn * cp.w * dd * dd;
            bond_f += (c0 + i > n) ? t : 0.0f;
        }
    }
    bond_f *= 2.0f;   // upper triangle counted twice

    // stats: one column-stripe of blocks per batch covers all rows exactly once
    if (blockIdx.y == 0) {
        double wd = (double)wn;
        double pxd=px, pyd=py, pzd=pz, gxd=gx, gyd=gy, gzd=gz;
        double st[16];
        st[0]=wd;
        st[1]=wd*pxd;  st[2]=wd*pyd;  st[3]=wd*pzd;
        st[4]=wd*gxd;  st[5]=wd*gyd;  st[6]=wd*gzd;
        st[7]=wd*pxd*gxd;  st[8]=wd*pxd*gyd;  st[9]=wd*pxd*gzd;
        st[10]=wd*pyd*gxd; st[11]=wd*pyd*gyd; st[12]=wd*pyd*gzd;
        st[13]=wd*pzd*gxd; st[14]=wd*pzd*gyd; st[15]=wd*pzd*gzd;
        #pragma unroll
        for (int off = 32; off > 0; off >>= 1) {
            #pragma unroll
            for (int k = 0; k < 16; k++) st[k] += __shfl_down(st[k], off, 64);
        }
        if (lane == 0) {
            #pragma unroll
            for (int k = 0; k < 16; k++) shred[wave][k] = st[k];
        }
        __syncthreads();
        if (tid < 16) {
            double s = shred[0][tid]+shred[1][tid]+shred[2][tid]+shred[3][tid];
            unsafeAtomicAdd(&stats[tid], s);
        }
    }

    // bond block-reduce -> atomic
    double bd = (double)bond_f;
    #pragma unroll
    for (int off = 32; off > 0; off >>= 1) bd += __shfl_down(bd, off, 64);
    __syncthreads();
    if (lane == 0) shred[wave][0] = bd;
    __syncthreads();
    if (tid == 0) {
        double bt = shred[0][0]+shred[1][0]+shred[2][0]+shred[3][0];
        unsafeAtomicAdd(bondp, bt);
    }

    // completion counter; __syncthreads drains each wave's outstanding atomics
    __shared__ int s_last;
    __syncthreads();
    if (tid == 0) {
        __threadfence();
        unsigned old = atomicAdd(cnt, 1u);
        s_last = (old == total - 1u) ? 1 : 0;
    }
    __syncthreads();
    if (!s_last) return;

    // ---- last block only: SVD per batch, align pass, final output ----
    __shared__ double Rm[MAXB][16];   // R[9], mu_pred[3], mu_gt[3], W
    if (tid < B) {
        double s[16];
        double* sb = ws + (size_t)tid * 16;
        for (int k = 0; k < 16; k++) s[k] = unsafeAtomicAdd(&sb[k], 0.0); // coherent read
        double W = s[0];
        double mup[3] = { s[1]/W, s[2]/W, s[3]/W };
        double mug[3] = { s[4]/W, s[5]/W, s[6]/W };
        double M[3][3];
        for (int i = 0; i < 3; i++)
            for (int j = 0; j < 3; j++)
                M[i][j] = s[7 + i*3 + j] - W * mup[i] * mug[j];

        double A[3][3];
        for (int i = 0; i < 3; i++)
            for (int j = 0; j < 3; j++) {
                double t = 0.0;
                for (int k = 0; k < 3; k++) t += M[k][i] * M[k][j];
                A[i][j] = t;
            }
        double V[3][3] = {{1,0,0},{0,1,0},{0,0,1}};
        for (int sweep = 0; sweep < 8; sweep++) {
            for (int pq = 0; pq < 3; pq++) {
                int pp_ = (pq == 2) ? 1 : 0;
                int qq_ = (pq == 0) ? 1 : 2;
                double apq = A[pp_][qq_];
                if (fabs(apq) < 1e-300) continue;
                double app = A[pp_][pp_], aqq = A[qq_][qq_];
                double theta = (aqq - app) / (2.0 * apq);
                double t = copysign(1.0, theta) / (fabs(theta) + sqrt(theta*theta + 1.0));
                double c = 1.0 / sqrt(t*t + 1.0), sn = t * c;
                A[pp_][pp_] = app - t * apq;
                A[qq_][qq_] = aqq + t * apq;
                A[pp_][qq_] = A[qq_][pp_] = 0.0;
                int r = 3 - pp_ - qq_;
                double arp = A[r][pp_], arq = A[r][qq_];
                A[r][pp_] = A[pp_][r] = c*arp - sn*arq;
                A[r][qq_] = A[qq_][r] = sn*arp + c*arq;
                for (int rr = 0; rr < 3; rr++) {
                    double vp = V[rr][pp_], vq = V[rr][qq_];
                    V[rr][pp_] = c*vp - sn*vq;
                    V[rr][qq_] = sn*vp + c*vq;
                }
            }
        }
        double d[3] = { A[0][0], A[1][1], A[2][2] };
        int idx[3] = {0, 1, 2};
        for (int i = 0; i < 2; i++)
            for (int j = i + 1; j < 3; j++)
                if (d[idx[j]] > d[idx[i]]) { int tt = idx[i]; idx[i] = idx[j]; idx[j] = tt; }
        double u[3][3], v[3][3];
        for (int i = 0; i < 3; i++) {
            int c_ = idx[i];
            double sv = sqrt(fmax(d[c_], 0.0));
            double inv = (sv > 1e-12) ? 1.0 / sv : 0.0;
            for (int r = 0; r < 3; r++) v[i][r] = V[r][c_];
            for (int r = 0; r < 3; r++) {
                double t = 0.0;
                for (int k = 0; k < 3; k++) t += M[r][k] * v[i][k];
                u[i][r] = t * inv;
            }
        }
        double detM = M[0][0]*(M[1][1]*M[2][2] - M[1][2]*M[2][1])
                    - M[0][1]*(M[1][0]*M[2][2] - M[1][2]*M[2][0])
                    + M[0][2]*(M[1][0]*M[2][1] - M[1][1]*M[2][0]);
        double sg2 = (detM < 0.0) ? -1.0 : 1.0;
        double* o = Rm[tid];
        for (int r = 0; r < 3; r++)
            for (int cc2 = 0; cc2 < 3; cc2++)
                o[r*3 + cc2] = u[0][r]*v[0][cc2] + u[1][r]*v[1][cc2] + sg2 * u[2][r]*v[2][cc2];
        for (int i = 0; i < 3; i++) o[9 + i]  = mup[i];
        for (int i = 0; i < 3; i++) o[12 + i] = mug[i];
        o[15] = W;
    }
    __syncthreads();

    double al = 0.0;
    for (int idx2 = tid; idx2 < B * N; idx2 += RT) {
        int bb = idx2 / N, nn = idx2 - bb * N;
        const float* pp = pred + ((size_t)bb * N + nn) * 3;
        const float* gg = gt   + ((size_t)bb * N + nn) * 3;
        double wv = w[(size_t)bb * N + nn];
        const double* o = Rm[bb];
        double xc0 = (double)gg[0]-o[12], xc1 = (double)gg[1]-o[13], xc2 = (double)gg[2]-o[14];
        double ax = o[0]*xc0 + o[1]*xc1 + o[2]*xc2 + o[9];
        double ay = o[3]*xc0 + o[4]*xc1 + o[5]*xc2 + o[10];
        double az = o[6]*xc0 + o[7]*xc1 + o[8]*xc2 + o[11];
        double ex = (double)pp[0]-ax, ey = (double)pp[1]-ay, ez = (double)pp[2]-az;
        double sq = ex*ex + ey*ey + ez*ez;
        al += (sq > 0.0) ? wv * sqrt(sq) : 0.0;
    }
    #pragma unroll
    for (int off = 32; off > 0; off >>= 1) al += __shfl_down(al, off, 64);
    __syncthreads();
    if (lane == 0) shred[wave][1] = al;
    __syncthreads();
    __shared__ double s_loss;
    if (tid == 0) {
        double at = shred[0][1]+shred[1][1]+shred[2][1]+shred[3][1];
        double tw = 0.0, twp = 0.0;
        for (int i = 0; i < B; i++) { double W = Rm[i][15]; tw += W; twp += W*W; }
        double bond = unsafeAtomicAdd(bondp, 0.0);  // coherent read (own add included)
        s_loss = at / tw + bond / twp;              // ALPHA_BOND = 1
    }
    __syncthreads();
    if (tid < B) {
        double h = (double)ht[tid];
        out[tid] = (float)(((h*h + 256.0) / ((h + 16.0)*(h + 16.0))) * s_loss); // SIGMA=16
    }
}

extern "C" void kernel_launch(void* const* d_in, const int* in_sizes, int n_in,
                              void* d_out, int out_size, void* d_ws, size_t ws_size,
                              hipStream_t stream) {
    const float* pred = (const float*)d_in[0];  // xpred_l [B,N,3]
    const float* gt   = (const float*)d_in[1];  // xGT_l   [B,N,3]
    const float* ht   = (const float*)d_in[2];  // ht      [B]
    const float* w    = (const float*)d_in[3];  // w_l     [B,N]
    int B = in_sizes[2];
    int N = in_sizes[3] / B;
    double* ws = (double*)d_ws;
    float* out = (float*)d_out;

    hipMemsetAsync(d_ws, 0, (size_t)(16 * B + 2) * sizeof(double), stream);

    dim3 grid((N + RT - 1) / RT, (N + CT - 1) / CT, B);
    unsigned total = grid.x * grid.y * grid.z;
    k_main<<<grid, dim3(RT), 0, stream>>>(pred, gt, ht, w, out, ws, N, B, total);
}

// Round 4
// 105.752 us; speedup vs baseline: 1.0184x; 1.0184x over previous
//
#include <hip/hip_runtime.h>
#include <math.h>

// Fully fused diffusion-loss kernel, contention-free communication.
// ws layout (doubles), all zeroed by kernel_launch's memset:
//   [0 .. B*GX*16)          per-(batch,row-block) stats partials (exclusive slots)
//   [B*GX*16 .. +total)     per-block bond partials (exclusive slots)
//   [+total]                (as uint32) block completion counter
// All cross-block traffic via device-scope atomics (coherent point); NO
// __threadfence -- the compiler's s_waitcnt vmcnt(0) before s_barrier orders
// each block's slot atomics before its counter bump.

#define RT 256      // rows per block (= threads)
#define CT 128      // cols per LDS tile
#define MAXB 8
#define MAXSTAT 1024

__global__ __launch_bounds__(RT, 4)
void k_main(const float* __restrict__ pred, const float* __restrict__ gt,
            const float* __restrict__ ht, const float* __restrict__ w,
            float* __restrict__ out, double* __restrict__ ws,
            int N, int B, unsigned total) {
    const int b    = blockIdx.z;
    const int bx   = blockIdx.x;
    const int r0   = bx * RT;
    const int c0   = blockIdx.y * CT;
    const int tid  = threadIdx.x;
    const int lane = tid & 63, wave = tid >> 6;
    const int GX   = gridDim.x;
    const unsigned linear = (blockIdx.z * gridDim.y + blockIdx.y) * GX + blockIdx.x;

    double* statsSlot = ws;                           // B*GX*16
    double* bondSlot  = ws + (size_t)B * GX * 16;     // total
    unsigned* cnt     = (unsigned*)(bondSlot + total);

    const float* p  = pred + (size_t)b * N * 3;
    const float* g  = gt   + (size_t)b * N * 3;
    const float* wb = w    + (size_t)b * N;

    __shared__ float4 sp4[CT], sg4[CT];
    __shared__ double shred[4][16];

    const int  n      = r0 + tid;
    const bool row_ok = (n < N);
    float px=0.f,py=0.f,pz=0.f,gx=0.f,gy=0.f,gz=0.f,wn=0.f;
    if (row_ok) {
        px = p[3*n]; py = p[3*n+1]; pz = p[3*n+2];
        gx = g[3*n]; gy = g[3*n+1]; gz = g[3*n+2];
        wn = wb[n];
    }

    // upper-triangle symmetry: tile contributes iff it contains some m > n
    const bool bond_active = (c0 + CT > r0 + 1) && (c0 < N);
    float bond_f = 0.0f;
    if (bond_active) {
        for (int i = tid; i < CT; i += RT) {
            int m = c0 + i;
            float4 a = make_float4(0.f,0.f,0.f,0.f), c = a;
            if (m < N) {
                a = make_float4(p[3*m], p[3*m+1], p[3*m+2], wb[m]);
                c = make_float4(g[3*m], g[3*m+1], g[3*m+2], 0.f);
            }
            sp4[i] = a; sg4[i] = c;
        }
        __syncthreads();
        if (row_ok) {
            const int cc = min(CT, N - c0);
            if (c0 >= r0 + RT) {
                // tile strictly above the diagonal: no predicate
                for (int i = 0; i < cc; i++) {
                    float4 cp = sp4[i], cg = sg4[i];
                    float dxp=px-cp.x, dyp=py-cp.y, dzp=pz-cp.z;
                    float dxg=gx-cg.x, dyg=gy-cg.y, dzg=gz-cg.z;
                    float dp = sqrtf(dxp*dxp+dyp*dyp+dzp*dzp);
                    float dg = sqrtf(dxg*dxg+dyg*dyg+dzg*dzg);
                    float dd = dp - dg;
                    bond_f += (wn*cp.w)*(dd*dd);
                }
            } else if (n < c0 + cc - 1) {   // waves fully below diagonal skip
                for (int i = 0; i < cc; i++) {
                    float4 cp = sp4[i], cg = sg4[i];
                    float dxp=px-cp.x, dyp=py-cp.y, dzp=pz-cp.z;
                    float dxg=gx-cg.x, dyg=gy-cg.y, dzg=gz-cg.z;
                    float dp = sqrtf(dxp*dxp+dyp*dyp+dzp*dzp);
                    float dg = sqrtf(dxg*dxg+dyg*dyg+dzg*dzg);
                    float dd = dp - dg;
                    float t  = (wn*cp.w)*(dd*dd);
                    bond_f += (c0 + i > n) ? t : 0.0f;
                }
            }
        }
    }
    bond_f *= 2.0f;   // strict upper triangle counted twice (diagonal is zero)

    // ---- stats: by==0 stripe covers every row exactly once ----
    if (blockIdx.y == 0) {
        double wd=wn, pxd=px,pyd=py,pzd=pz, gxd=gx,gyd=gy,gzd=gz;
        double st[16] = {wd, wd*pxd, wd*pyd, wd*pzd, wd*gxd, wd*gyd, wd*gzd,
                         wd*pxd*gxd, wd*pxd*gyd, wd*pxd*gzd,
                         wd*pyd*gxd, wd*pyd*gyd, wd*pyd*gzd,
                         wd*pzd*gxd, wd*pzd*gyd, wd*pzd*gzd};
        #pragma unroll
        for (int off = 32; off > 0; off >>= 1) {
            #pragma unroll
            for (int k = 0; k < 16; k++) st[k] += __shfl_down(st[k], off, 64);
        }
        if (lane == 0) {
            #pragma unroll
            for (int k = 0; k < 16; k++) shred[wave][k] = st[k];
        }
        __syncthreads();
        if (tid < 16) {
            double s = shred[0][tid]+shred[1][tid]+shred[2][tid]+shred[3][tid];
            unsafeAtomicAdd(&statsSlot[((size_t)b*GX + bx)*16 + tid], s); // exclusive slot
        }
        __syncthreads();   // shred reused below
    }

    // ---- bond block-reduce -> exclusive slot ----
    double bd = (double)bond_f;
    #pragma unroll
    for (int off = 32; off > 0; off >>= 1) bd += __shfl_down(bd, off, 64);
    if (lane == 0) shred[wave][0] = bd;
    __syncthreads();
    if (tid == 0 && bond_active) {
        double bt = shred[0][0]+shred[1][0]+shred[2][0]+shred[3][0];
        unsafeAtomicAdd(&bondSlot[linear], bt);                          // exclusive slot
    }

    // ---- completion counter (barrier drains this block's atomics first) ----
    __shared__ unsigned s_old;
    __syncthreads();
    if (tid == 0) s_old = atomicAdd(cnt, 1u);
    __syncthreads();
    if (s_old != total - 1u) return;

    // ================= last block only =================
    const int nstat = B * GX * 16;
    __shared__ double sstat[MAXSTAT];
    for (int i = tid; i < nstat; i += RT)
        sstat[i] = unsafeAtomicAdd(&statsSlot[i], 0.0);   // coherent read

    double bsum = 0.0;
    for (unsigned i = tid; i < total; i += RT)
        bsum += unsafeAtomicAdd(&bondSlot[i], 0.0);
    #pragma unroll
    for (int off = 32; off > 0; off >>= 1) bsum += __shfl_down(bsum, off, 64);
    if (lane == 0) shred[wave][1] = bsum;
    __syncthreads();   // sstat + shred ready

    __shared__ double s_bond;
    __shared__ float  Rf[MAXB][15];
    __shared__ double Wd[MAXB];
    if (tid == 0) s_bond = shred[0][1]+shred[1][1]+shred[2][1]+shred[3][1];

    if (tid < B) {
        double s[16];
        for (int k = 0; k < 16; k++) {
            double acc = 0.0;
            for (int j = 0; j < GX; j++) acc += sstat[((size_t)tid*GX + j)*16 + k];
            s[k] = acc;
        }
        double W = s[0];
        double mup[3] = { s[1]/W, s[2]/W, s[3]/W };
        double mug[3] = { s[4]/W, s[5]/W, s[6]/W };
        double M[3][3];
        for (int i = 0; i < 3; i++)
            for (int j = 0; j < 3; j++)
                M[i][j] = s[7 + i*3 + j] - W * mup[i] * mug[j];

        double A[3][3];
        for (int i = 0; i < 3; i++)
            for (int j = 0; j < 3; j++) {
                double t = 0.0;
                for (int k = 0; k < 3; k++) t += M[k][i] * M[k][j];
                A[i][j] = t;
            }
        double V[3][3] = {{1,0,0},{0,1,0},{0,0,1}};
        for (int sweep = 0; sweep < 8; sweep++) {
            for (int pq = 0; pq < 3; pq++) {
                int pp_ = (pq == 2) ? 1 : 0;
                int qq_ = (pq == 0) ? 1 : 2;
                double apq = A[pp_][qq_];
                if (fabs(apq) < 1e-300) continue;
                double app = A[pp_][pp_], aqq = A[qq_][qq_];
                double theta = (aqq - app) / (2.0 * apq);
                double t = copysign(1.0, theta) / (fabs(theta) + sqrt(theta*theta + 1.0));
                double cj = 1.0 / sqrt(t*t + 1.0), sn = t * cj;
                A[pp_][pp_] = app - t * apq;
                A[qq_][qq_] = aqq + t * apq;
                A[pp_][qq_] = A[qq_][pp_] = 0.0;
                int r = 3 - pp_ - qq_;
                double arp = A[r][pp_], arq = A[r][qq_];
                A[r][pp_] = A[pp_][r] = cj*arp - sn*arq;
                A[r][qq_] = A[qq_][r] = sn*arp + cj*arq;
                for (int rr = 0; rr < 3; rr++) {
                    double vp = V[rr][pp_], vq = V[rr][qq_];
                    V[rr][pp_] = cj*vp - sn*vq;
                    V[rr][qq_] = sn*vp + cj*vq;
                }
            }
        }
        double d[3] = { A[0][0], A[1][1], A[2][2] };
        int idx[3] = {0, 1, 2};   // sort descending: det-fix flips smallest sv
        for (int i = 0; i < 2; i++)
            for (int j = i + 1; j < 3; j++)
                if (d[idx[j]] > d[idx[i]]) { int tt = idx[i]; idx[i] = idx[j]; idx[j] = tt; }
        double u[3][3], v[3][3];
        for (int i = 0; i < 3; i++) {
            int c_ = idx[i];
            double sv = sqrt(fmax(d[c_], 0.0));
            double inv = (sv > 1e-12) ? 1.0 / sv : 0.0;
            for (int r = 0; r < 3; r++) v[i][r] = V[r][c_];
            for (int r = 0; r < 3; r++) {
                double t = 0.0;
                for (int k = 0; k < 3; k++) t += M[r][k] * v[i][k];
                u[i][r] = t * inv;
            }
        }
        double detM = M[0][0]*(M[1][1]*M[2][2] - M[1][2]*M[2][1])
                    - M[0][1]*(M[1][0]*M[2][2] - M[1][2]*M[2][0])
                    + M[0][2]*(M[1][0]*M[2][1] - M[1][1]*M[2][0]);
        double sg2 = (detM < 0.0) ? -1.0 : 1.0;
        for (int r = 0; r < 3; r++)
            for (int cc2 = 0; cc2 < 3; cc2++)
                Rf[tid][r*3+cc2] = (float)(u[0][r]*v[0][cc2] + u[1][r]*v[1][cc2]
                                           + sg2 * u[2][r]*v[2][cc2]);
        for (int i = 0; i < 3; i++) Rf[tid][9 + i]  = (float)mup[i];
        for (int i = 0; i < 3; i++) Rf[tid][12 + i] = (float)mug[i];
        Wd[tid] = W;
    }
    __syncthreads();

    // align pass (f32 math, f64 accumulate)
    double al = 0.0;
    for (int bb = 0; bb < B; bb++) {
        float R0=Rf[bb][0], R1=Rf[bb][1], R2=Rf[bb][2];
        float R3=Rf[bb][3], R4=Rf[bb][4], R5=Rf[bb][5];
        float R6=Rf[bb][6], R7=Rf[bb][7], R8=Rf[bb][8];
        float mp0=Rf[bb][9], mp1=Rf[bb][10], mp2=Rf[bb][11];
        float mg0=Rf[bb][12], mg1=Rf[bb][13], mg2=Rf[bb][14];
        const float* pp  = pred + (size_t)bb * N * 3;
        const float* gg  = gt   + (size_t)bb * N * 3;
        const float* wwb = w    + (size_t)bb * N;
        for (int nn = tid; nn < N; nn += RT) {
            float x0 = gg[3*nn]-mg0, x1 = gg[3*nn+1]-mg1, x2 = gg[3*nn+2]-mg2;
            float ax = fmaf(R0,x0, fmaf(R1,x1, fmaf(R2,x2, mp0)));
            float ay = fmaf(R3,x0, fmaf(R4,x1, fmaf(R5,x2, mp1)));
            float az = fmaf(R6,x0, fmaf(R7,x1, fmaf(R8,x2, mp2)));
            float ex = pp[3*nn]-ax, ey = pp[3*nn+1]-ay, ez = pp[3*nn+2]-az;
            float sq = ex*ex + ey*ey + ez*ez;
            al += (double)(wwb[nn] * sqrtf(sq));
        }
    }
    #pragma unroll
    for (int off = 32; off > 0; off >>= 1) al += __shfl_down(al, off, 64);
    if (lane == 0) shred[wave][2] = al;
    __syncthreads();

    __shared__ double s_loss;
    if (tid == 0) {
        double at = shred[0][2]+shred[1][2]+shred[2][2]+shred[3][2];
        double tw = 0.0, twp = 0.0;
        for (int i = 0; i < B; i++) { double W = Wd[i]; tw += W; twp += W*W; }
        s_loss = at / tw + s_bond / twp;    // ALPHA_BOND = 1
    }
    __syncthreads();
    if (tid < B) {
        double h = (double)ht[tid];
        out[tid] = (float)(((h*h + 256.0) / ((h + 16.0)*(h + 16.0))) * s_loss); // SIGMA=16
    }
}

extern "C" void kernel_launch(void* const* d_in, const int* in_sizes, int n_in,
                              void* d_out, int out_size, void* d_ws, size_t ws_size,
                              hipStream_t stream) {
    const float* pred = (const float*)d_in[0];  // xpred_l [B,N,3]
    const float* gt   = (const float*)d_in[1];  // xGT_l   [B,N,3]
    const float* ht   = (const float*)d_in[2];  // ht      [B]
    const float* w    = (const float*)d_in[3];  // w_l     [B,N]
    int B = in_sizes[2];
    int N = in_sizes[3] / B;
    double* ws = (double*)d_ws;
    float* out = (float*)d_out;

    int gx = (N + RT - 1) / RT;
    int gy = (N + CT - 1) / CT;
    unsigned total = (unsigned)(gx * gy * B);
    size_t zbytes = ((size_t)B * gx * 16 + total + 2) * sizeof(double);
    hipMemsetAsync(d_ws, 0, zbytes, stream);

    k_main<<<dim3(gx, gy, B), dim3(RT), 0, stream>>>(pred, gt, ht, w, out, ws, N, B, total);
}

// Round 5
// 100.543 us; speedup vs baseline: 1.0711x; 1.0518x over previous
//
#include <hip/hip_runtime.h>
#include <math.h>

// Two-kernel diffusion loss. Cross-kernel communication via plain stores to
// exclusive slots (kernel boundary on the same stream guarantees visibility;
// no atomics, no memset, no completion counter).
//
// ws layout (doubles):
//   [0 .. B*GX*16)          stats partials, slot (b*GX+bx)*16+k  (by==0 blocks)
//   [B*GX*16 .. +total)     bond partials, slot = linear block id (all blocks)

#define RT 256      // rows per block (= threads)
#define CT 64       // cols per LDS tile
#define MAXB 8
#define MAXGX 16

__global__ __launch_bounds__(RT, 4)
void k_bond_stats(const float* __restrict__ pred, const float* __restrict__ gt,
                  const float* __restrict__ w, double* __restrict__ ws,
                  int N, int B) {
    const int b    = blockIdx.z;
    const int bx   = blockIdx.x;
    const int r0   = bx * RT;
    const int c0   = blockIdx.y * CT;
    const int tid  = threadIdx.x;
    const int lane = tid & 63, wave = tid >> 6;
    const int GX   = gridDim.x;
    const unsigned linear = (blockIdx.z * gridDim.y + blockIdx.y) * GX + blockIdx.x;

    double* statsSlot = ws;                           // B*GX*16
    double* bondSlot  = ws + (size_t)B * GX * 16;     // one per block

    const float* p  = pred + (size_t)b * N * 3;
    const float* g  = gt   + (size_t)b * N * 3;
    const float* wb = w    + (size_t)b * N;

    __shared__ float4 sp4[CT], sg4[CT];
    __shared__ double shred[4][16];

    const int  n      = r0 + tid;
    const bool row_ok = (n < N);
    float px=0.f,py=0.f,pz=0.f,gx=0.f,gy=0.f,gz=0.f,wn=0.f;
    if (row_ok) {
        px = p[3*n]; py = p[3*n+1]; pz = p[3*n+2];
        gx = g[3*n]; gy = g[3*n+1]; gz = g[3*n+2];
        wn = wb[n];
    }

    // strict upper triangle (m > n), counted twice
    const bool bond_active = (c0 + CT > r0 + 1) && (c0 < N);
    float bond_f = 0.0f;
    if (bond_active) {
        for (int i = tid; i < CT; i += RT) {
            int m = c0 + i;
            float4 a = make_float4(0.f,0.f,0.f,0.f), c = a;
            if (m < N) {
                a = make_float4(p[3*m], p[3*m+1], p[3*m+2], wb[m]);
                c = make_float4(g[3*m], g[3*m+1], g[3*m+2], 0.f);
            }
            sp4[i] = a; sg4[i] = c;
        }
        __syncthreads();
        if (row_ok) {
            const int cc = min(CT, N - c0);
            if (c0 >= r0 + RT) {          // strictly above diagonal band
                #pragma unroll 4
                for (int i = 0; i < cc; i++) {
                    float4 cp = sp4[i], cg = sg4[i];
                    float dxp=px-cp.x, dyp=py-cp.y, dzp=pz-cp.z;
                    float dxg=gx-cg.x, dyg=gy-cg.y, dzg=gz-cg.z;
                    float dp = sqrtf(dxp*dxp+dyp*dyp+dzp*dzp);
                    float dg = sqrtf(dxg*dxg+dyg*dyg+dzg*dzg);
                    float dd = dp - dg;
                    bond_f += (wn*cp.w)*(dd*dd);
                }
            } else if (n < c0 + cc - 1) { // diagonal band, predicated
                #pragma unroll 4
                for (int i = 0; i < cc; i++) {
                    float4 cp = sp4[i], cg = sg4[i];
                    float dxp=px-cp.x, dyp=py-cp.y, dzp=pz-cp.z;
                    float dxg=gx-cg.x, dyg=gy-cg.y, dzg=gz-cg.z;
                    float dp = sqrtf(dxp*dxp+dyp*dyp+dzp*dzp);
                    float dg = sqrtf(dxg*dxg+dyg*dyg+dzg*dzg);
                    float dd = dp - dg;
                    float t  = (wn*cp.w)*(dd*dd);
                    bond_f += (c0 + i > n) ? t : 0.0f;
                }
            }
        }
    }
    bond_f *= 2.0f;

    // stats: by==0 stripe covers each row exactly once; plain-store slot
    if (blockIdx.y == 0) {
        double wd=wn, pxd=px,pyd=py,pzd=pz, gxd=gx,gyd=gy,gzd=gz;
        double st[16] = {wd, wd*pxd, wd*pyd, wd*pzd, wd*gxd, wd*gyd, wd*gzd,
                         wd*pxd*gxd, wd*pxd*gyd, wd*pxd*gzd,
                         wd*pyd*gxd, wd*pyd*gyd, wd*pyd*gzd,
                         wd*pzd*gxd, wd*pzd*gyd, wd*pzd*gzd};
        #pragma unroll
        for (int off = 32; off > 0; off >>= 1) {
            #pragma unroll
            for (int k = 0; k < 16; k++) st[k] += __shfl_down(st[k], off, 64);
        }
        if (lane == 0) {
            #pragma unroll
            for (int k = 0; k < 16; k++) shred[wave][k] = st[k];
        }
        __syncthreads();
        if (tid < 16)
            statsSlot[((size_t)b*GX + bx)*16 + tid] =
                shred[0][tid]+shred[1][tid]+shred[2][tid]+shred[3][tid];
        __syncthreads();   // shred reused below
    }

    // bond block-reduce -> plain-store slot (every block writes, maybe 0)
    double bd = (double)bond_f;
    #pragma unroll
    for (int off = 32; off > 0; off >>= 1) bd += __shfl_down(bd, off, 64);
    if (lane == 0) shred[wave][0] = bd;
    __syncthreads();
    if (tid == 0)
        bondSlot[linear] = shred[0][0]+shred[1][0]+shred[2][0]+shred[3][0];
}

__global__ __launch_bounds__(RT, 1)
void k_tail(const float* __restrict__ pred, const float* __restrict__ gt,
            const float* __restrict__ ht, const float* __restrict__ w,
            float* __restrict__ out, const double* __restrict__ ws,
            int N, int B, int GX, unsigned total) {
    const int tid  = threadIdx.x;
    const int lane = tid & 63, wave = tid >> 6;
    const double* statsSlot = ws;
    const double* bondSlot  = ws + (size_t)B * GX * 16;

    __shared__ double sstat[MAXB][16];
    __shared__ double shred[4][16];
    __shared__ float  Rf[MAXB][15];
    __shared__ double Wd[MAXB];
    __shared__ double s_bond, s_loss;

    // reduce stats slots: thread (b*16+k) sums over GX row-blocks
    if (tid < B * 16) {
        int bb = tid >> 4, k = tid & 15;
        double acc = 0.0;
        for (int j = 0; j < GX; j++) acc += statsSlot[((size_t)bb*GX + j)*16 + k];
        sstat[bb][k] = acc;
    }

    // reduce bond slots (plain loads)
    double bsum = 0.0;
    for (unsigned i = tid; i < total; i += RT) bsum += bondSlot[i];
    #pragma unroll
    for (int off = 32; off > 0; off >>= 1) bsum += __shfl_down(bsum, off, 64);
    if (lane == 0) shred[wave][0] = bsum;
    __syncthreads();
    if (tid == 0) s_bond = shred[0][0]+shred[1][0]+shred[2][0]+shred[3][0];

    // per-batch Kabsch (f64, one thread each)
    if (tid < B) {
        const double* s = sstat[tid];
        double W = s[0];
        double mup[3] = { s[1]/W, s[2]/W, s[3]/W };
        double mug[3] = { s[4]/W, s[5]/W, s[6]/W };
        double M[3][3];
        for (int i = 0; i < 3; i++)
            for (int j = 0; j < 3; j++)
                M[i][j] = s[7 + i*3 + j] - W * mup[i] * mug[j];
        double A[3][3];
        for (int i = 0; i < 3; i++)
            for (int j = 0; j < 3; j++) {
                double t = 0.0;
                for (int k = 0; k < 3; k++) t += M[k][i] * M[k][j];
                A[i][j] = t;
            }
        double V[3][3] = {{1,0,0},{0,1,0},{0,0,1}};
        for (int sweep = 0; sweep < 6; sweep++) {
            for (int pq = 0; pq < 3; pq++) {
                int pp_ = (pq == 2) ? 1 : 0;
                int qq_ = (pq == 0) ? 1 : 2;
                double apq = A[pp_][qq_];
                if (fabs(apq) < 1e-300) continue;
                double app = A[pp_][pp_], aqq = A[qq_][qq_];
                double theta = (aqq - app) / (2.0 * apq);
                double t = copysign(1.0, theta) / (fabs(theta) + sqrt(theta*theta + 1.0));
                double cj = 1.0 / sqrt(t*t + 1.0), sn = t * cj;
                A[pp_][pp_] = app - t * apq;
                A[qq_][qq_] = aqq + t * apq;
                A[pp_][qq_] = A[qq_][pp_] = 0.0;
                int r = 3 - pp_ - qq_;
                double arp = A[r][pp_], arq = A[r][qq_];
                A[r][pp_] = A[pp_][r] = cj*arp - sn*arq;
                A[r][qq_] = A[qq_][r] = sn*arp + cj*arq;
                for (int rr = 0; rr < 3; rr++) {
                    double vp = V[rr][pp_], vq = V[rr][qq_];
                    V[rr][pp_] = cj*vp - sn*vq;
                    V[rr][qq_] = sn*vp + cj*vq;
                }
            }
        }
        double d[3] = { A[0][0], A[1][1], A[2][2] };
        int idx[3] = {0, 1, 2};   // descending: det-fix flips smallest sv
        for (int i = 0; i < 2; i++)
            for (int j = i + 1; j < 3; j++)
                if (d[idx[j]] > d[idx[i]]) { int tt = idx[i]; idx[i] = idx[j]; idx[j] = tt; }
        double u[3][3], v[3][3];
        for (int i = 0; i < 3; i++) {
            int c_ = idx[i];
            double sv = sqrt(fmax(d[c_], 0.0));
            double inv = (sv > 1e-12) ? 1.0 / sv : 0.0;
            for (int r = 0; r < 3; r++) v[i][r] = V[r][c_];
            for (int r = 0; r < 3; r++) {
                double t = 0.0;
                for (int k = 0; k < 3; k++) t += M[r][k] * v[i][k];
                u[i][r] = t * inv;
            }
        }
        double detM = M[0][0]*(M[1][1]*M[2][2] - M[1][2]*M[2][1])
                    - M[0][1]*(M[1][0]*M[2][2] - M[1][2]*M[2][0])
                    + M[0][2]*(M[1][0]*M[2][1] - M[1][1]*M[2][0]);
        double sg2 = (detM < 0.0) ? -1.0 : 1.0;
        for (int r = 0; r < 3; r++)
            for (int cc2 = 0; cc2 < 3; cc2++)
                Rf[tid][r*3+cc2] = (float)(u[0][r]*v[0][cc2] + u[1][r]*v[1][cc2]
                                           + sg2 * u[2][r]*v[2][cc2]);
        for (int i = 0; i < 3; i++) Rf[tid][9 + i]  = (float)mup[i];
        for (int i = 0; i < 3; i++) Rf[tid][12 + i] = (float)mug[i];
        Wd[tid] = W;
    }
    __syncthreads();

    // align pass (f32 math, f64 accumulate)
    double al = 0.0;
    for (int bb = 0; bb < B; bb++) {
        float R0=Rf[bb][0], R1=Rf[bb][1], R2=Rf[bb][2];
        float R3=Rf[bb][3], R4=Rf[bb][4], R5=Rf[bb][5];
        float R6=Rf[bb][6], R7=Rf[bb][7], R8=Rf[bb][8];
        float mp0=Rf[bb][9],  mp1=Rf[bb][10], mp2=Rf[bb][11];
        float mg0=Rf[bb][12], mg1=Rf[bb][13], mg2=Rf[bb][14];
        const float* pp  = pred + (size_t)bb * N * 3;
        const float* gg  = gt   + (size_t)bb * N * 3;
        const float* wwb = w    + (size_t)bb * N;
        for (int nn = tid; nn < N; nn += RT) {
            float x0 = gg[3*nn]-mg0, x1 = gg[3*nn+1]-mg1, x2 = gg[3*nn+2]-mg2;
            float ax = fmaf(R0,x0, fmaf(R1,x1, fmaf(R2,x2, mp0)));
            float ay = fmaf(R3,x0, fmaf(R4,x1, fmaf(R5,x2, mp1)));
            float az = fmaf(R6,x0, fmaf(R7,x1, fmaf(R8,x2, mp2)));
            float ex = pp[3*nn]-ax, ey = pp[3*nn+1]-ay, ez = pp[3*nn+2]-az;
            float sq = ex*ex + ey*ey + ez*ez;
            al += (double)(wwb[nn] * sqrtf(sq));
        }
    }
    #pragma unroll
    for (int off = 32; off > 0; off >>= 1) al += __shfl_down(al, off, 64);
    if (lane == 0) shred[wave][1] = al;
    __syncthreads();
    if (tid == 0) {
        double at = shred[0][1]+shred[1][1]+shred[2][1]+shred[3][1];
        double tw = 0.0, twp = 0.0;
        for (int i = 0; i < B; i++) { double W = Wd[i]; tw += W; twp += W*W; }
        s_loss = at / tw + s_bond / twp;    // ALPHA_BOND = 1
    }
    __syncthreads();
    if (tid < B) {
        double h = (double)ht[tid];
        out[tid] = (float)(((h*h + 256.0) / ((h + 16.0)*(h + 16.0))) * s_loss); // SIGMA=16
    }
}

extern "C" void kernel_launch(void* const* d_in, const int* in_sizes, int n_in,
                              void* d_out, int out_size, void* d_ws, size_t ws_size,
                              hipStream_t stream) {
    const float* pred = (const float*)d_in[0];  // xpred_l [B,N,3]
    const float* gt   = (const float*)d_in[1];  // xGT_l   [B,N,3]
    const float* ht   = (const float*)d_in[2];  // ht      [B]
    const float* w    = (const float*)d_in[3];  // w_l     [B,N]
    int B = in_sizes[2];
    int N = in_sizes[3] / B;
    double* ws = (double*)d_ws;
    float* out = (float*)d_out;

    int gx = (N + RT - 1) / RT;
    int gy = (N + CT - 1) / CT;
    unsigned total = (unsigned)(gx * gy * B);

    k_bond_stats<<<dim3(gx, gy, B), dim3(RT), 0, stream>>>(pred, gt, w, ws, N, B);
    k_tail<<<dim3(1), dim3(RT), 0, stream>>>(pred, gt, ht, w, out, ws, N, B, gx, total);
}